// Round 1
// baseline (12158.289 us; speedup 1.0000x reference)
//
#include <hip/hip_runtime.h>

typedef _Float16 half8 __attribute__((ext_vector_type(8)));
typedef _Float16 half4v __attribute__((ext_vector_type(4)));
typedef float floatx4 __attribute__((ext_vector_type(4)));

#define MFMA16(a, b, c) __builtin_amdgcn_mfma_f32_16x16x32_f16(a, b, c, 0, 0, 0)

// ws layout: [0,2MB) WxT fp16 (1024x1024, [j][d]); [2MB,4MB) WhT fp16 ([j][k]);
// [4MB, +512B) barrier counters (group g at +g*16 uints).

// ---------------- prep: transpose Wx,Wh -> fp16, zero barrier counters ----------------
__global__ __launch_bounds__(256) void prep_kernel(
    const float* __restrict__ Wx, const float* __restrict__ Wh,
    _Float16* __restrict__ WxT, _Float16* __restrict__ WhT,
    unsigned int* __restrict__ bar)
{
    __shared__ float tile[32][33];
    int bid = blockIdx.x;
    int tid = threadIdx.x;
    if (bid == 0 && tid < 128) bar[tid] = 0u;
    const float* src = (bid < 1024) ? Wx : Wh;
    _Float16* dst = (bid < 1024) ? WxT : WhT;
    int tb = bid & 1023;
    int d0 = (tb >> 5) << 5;   // source row tile (k dim)
    int j0 = (tb & 31) << 5;   // source col tile (j dim)
    int r  = tid >> 3;         // 0..31
    int c4 = (tid & 7) << 2;   // 0,4,..,28
    float4 v = *(const float4*)(src + (long)(d0 + r) * 1024 + j0 + c4);
    tile[r][c4 + 0] = v.x; tile[r][c4 + 1] = v.y;
    tile[r][c4 + 2] = v.z; tile[r][c4 + 3] = v.w;
    __syncthreads();
    half4v o;
    o[0] = (_Float16)tile[c4 + 0][r];
    o[1] = (_Float16)tile[c4 + 1][r];
    o[2] = (_Float16)tile[c4 + 2][r];
    o[3] = (_Float16)tile[c4 + 3][r];
    // dst[(j0+r)][d0+c4 .. +4] = src[d0+c4..][j0+r]
    *(half4v*)(dst + (long)(j0 + r) * 1024 + d0 + c4) = o;
}

// ---------------- phase 1: out[r][j] = b[j] + sum_d x[r][d]*Wx[d][j] ----------------
// 128x128 tile per block, BK=32, 256 threads (4 waves, each 64x64 = 4x4 MFMA tiles).
#define LDA 40  // halves per A row in LDS (32 + 8 pad)

__global__ __launch_bounds__(256, 2) void gemm_xw(
    const float* __restrict__ x, const _Float16* __restrict__ WxT,
    const float* __restrict__ bias, float* __restrict__ out)
{
    __shared__ _Float16 As[128 * LDA];   // 10 KB
    __shared__ _Float16 Bs[128 * 32];    // 8 KB, chunk-swizzled
    int tid = threadIdx.x;
    int lane = tid & 63;
    int w = tid >> 6;
    int q = lane >> 4;
    int l16 = lane & 15;
    int wm = w >> 1, wn = w & 1;
    int bm = blockIdx.x >> 3;
    int bn = blockIdx.x & 7;
    long M0 = (long)bm * 128;
    int N0 = bn << 7;

    floatx4 acc[4][4] = {};

    int arow = tid >> 1;
    int ahalf = tid & 1;
    const float* aptr = x + (M0 + arow) * 1024 + (ahalf << 4);
    _Float16* awr = As + arow * LDA + (ahalf << 4);

    for (int kb = 0; kb < 32; ++kb) {
        __syncthreads();
        // stage A: 128x32 fp32 -> fp16
        {
            const float4* ap = (const float4*)(aptr + (kb << 5));
            float4 v0 = ap[0], v1 = ap[1], v2 = ap[2], v3 = ap[3];
            half8 h0v, h1v;
            h0v[0] = (_Float16)v0.x; h0v[1] = (_Float16)v0.y;
            h0v[2] = (_Float16)v0.z; h0v[3] = (_Float16)v0.w;
            h0v[4] = (_Float16)v1.x; h0v[5] = (_Float16)v1.y;
            h0v[6] = (_Float16)v1.z; h0v[7] = (_Float16)v1.w;
            h1v[0] = (_Float16)v2.x; h1v[1] = (_Float16)v2.y;
            h1v[2] = (_Float16)v2.z; h1v[3] = (_Float16)v2.w;
            h1v[4] = (_Float16)v3.x; h1v[5] = (_Float16)v3.y;
            h1v[6] = (_Float16)v3.z; h1v[7] = (_Float16)v3.w;
            *(half8*)(awr) = h0v;
            *(half8*)(awr + 8) = h1v;
        }
        // stage B: Bs chunk (j, cp) holds global k-chunk c = cp ^ ((j>>1)&3)
        #pragma unroll
        for (int i = 0; i < 2; ++i) {
            int chunkid = (i << 8) + tid;       // 0..511
            int j = chunkid >> 2;               // 0..127
            int cp = chunkid & 3;
            int c = cp ^ ((j >> 1) & 3);
            uint4 vv = *(const uint4*)(WxT + (long)(N0 + j) * 1024 + (kb << 5) + (c << 3));
            *(uint4*)(Bs + (chunkid << 3)) = vv;
        }
        __syncthreads();
        half8 af[4], bf[4];
        #pragma unroll
        for (int i = 0; i < 4; ++i)
            af[i] = *(const half8*)(As + (wm * 64 + i * 16 + l16) * LDA + q * 8);
        #pragma unroll
        for (int jt = 0; jt < 4; ++jt) {
            int jr = wn * 64 + jt * 16 + l16;
            int cp = q ^ ((jr >> 1) & 3);
            bf[jt] = *(const half8*)(Bs + jr * 32 + cp * 8);
        }
        #pragma unroll
        for (int i = 0; i < 4; ++i) {
            #pragma unroll
            for (int jt = 0; jt < 4; ++jt)
                acc[i][jt] = MFMA16(af[i], bf[jt], acc[i][jt]);
        }
    }
    // epilogue: C[row=q*4+reg][col=l16] per 16x16 tile; add bias
    #pragma unroll
    for (int jt = 0; jt < 4; ++jt) {
        int col = N0 + wn * 64 + jt * 16 + l16;
        float bv = bias[col];
        #pragma unroll
        for (int i = 0; i < 4; ++i) {
            long row = M0 + wm * 64 + i * 16 + q * 4;
            #pragma unroll
            for (int r2 = 0; r2 < 4; ++r2)
                out[(row + r2) * 1024 + col] = acc[i][jt][r2] + bv;
        }
    }
}

// ---------------- phase 2: persistent scan, h_t = tanh(xw_t + h_{t-1} @ Wh) ----------------
// 256 blocks: group g = bid>>5 owns rows [g*16,g*16+16); block c = bid&31 owns cols [c*32,c*32+32).
// Wh column-slice resident in LDS for all 512 steps. Group barrier = monotonic atomic counter.
#define WROW 1032  // halves per Wh LDS row (1024 + 8 pad)

__global__ __launch_bounds__(256, 1) void rnn_scan(
    const float* __restrict__ h0, const _Float16* __restrict__ WhT,
    float* __restrict__ out, unsigned int* __restrict__ bar)
{
    __shared__ _Float16 whs[32 * WROW];  // ~66 KB
    __shared__ float red[4 * 512];       // 8 KB
    int tid = threadIdx.x;
    int lane = tid & 63, w = tid >> 6;
    int q = lane >> 4, l16 = lane & 15;
    int g = blockIdx.x >> 5, c = blockIdx.x & 31;
    int n0 = g << 4, j0 = c << 5;
    unsigned int* cnt = bar + g * 16;

    // load Wh slice once: whs[jl][k] = Wh[k][j0+jl] (from WhT[j0+jl][k])
    for (int i = tid; i < 32 * 128; i += 256) {
        int jl = i >> 7, ch = i & 127;
        *(uint4*)(whs + jl * WROW + (ch << 3)) =
            *(const uint4*)(WhT + (long)(j0 + jl) * 1024 + (ch << 3));
    }
    __syncthreads();

    const long ST = 512L * 1024L;  // out row stride per n
    for (int t = 0; t < 512; ++t) {
        const float* hrow;
        long rstride;
        if (t == 0) { hrow = h0 + (long)n0 * 1024; rstride = 1024; }
        else        { hrow = out + (long)n0 * ST + (long)(t - 1) * 1024; rstride = ST; }
        const float* hp = hrow + (long)l16 * rstride + (w << 8);

        floatx4 acc0 = {0.f, 0.f, 0.f, 0.f};
        floatx4 acc1 = {0.f, 0.f, 0.f, 0.f};
        #pragma unroll
        for (int kc = 0; kc < 8; ++kc) {
            const float4* f = (const float4*)(hp + (kc << 5) + (q << 3));
            float4 v0 = f[0], v1 = f[1];
            half8 a;
            a[0] = (_Float16)v0.x; a[1] = (_Float16)v0.y;
            a[2] = (_Float16)v0.z; a[3] = (_Float16)v0.w;
            a[4] = (_Float16)v1.x; a[5] = (_Float16)v1.y;
            a[6] = (_Float16)v1.z; a[7] = (_Float16)v1.w;
            int koff = (w << 8) + (kc << 5) + (q << 3);
            half8 b0 = *(const half8*)(whs + l16 * WROW + koff);
            half8 b1 = *(const half8*)(whs + (16 + l16) * WROW + koff);
            acc0 = MFMA16(a, b0, acc0);
            acc1 = MFMA16(a, b1, acc1);
        }
        // cross-wave K reduction via LDS: element e = m*32 + jl
        #pragma unroll
        for (int r2 = 0; r2 < 4; ++r2) {
            int m = (q << 2) + r2;
            red[(w << 9) + (m << 5) + l16]      = acc0[r2];
            red[(w << 9) + (m << 5) + 16 + l16] = acc1[r2];
        }
        __syncthreads();
        #pragma unroll
        for (int e = tid; e < 512; e += 256) {
            float s = red[e] + red[512 + e] + red[1024 + e] + red[1536 + e];
            int m = e >> 5, jl = e & 31;
            long oidx = (long)(n0 + m) * ST + (long)t * 1024 + j0 + jl;
            out[oidx] = tanhf(s + out[oidx]);
        }
        __syncthreads();  // all stores issued (implies vmcnt drain) before arrival
        if (tid == 0) {
            __threadfence();  // agent-scope: write back XCD L2 so peers see h_t
            __hip_atomic_fetch_add(cnt, 1u, __ATOMIC_RELEASE, __HIP_MEMORY_SCOPE_AGENT);
            unsigned int target = (unsigned int)(t + 1) * 32u;
            while (__hip_atomic_load(cnt, __ATOMIC_ACQUIRE, __HIP_MEMORY_SCOPE_AGENT) < target)
                __builtin_amdgcn_s_sleep(2);
            __threadfence();
        }
        __syncthreads();
    }
}

extern "C" void kernel_launch(void* const* d_in, const int* in_sizes, int n_in,
                              void* d_out, int out_size, void* d_ws, size_t ws_size,
                              hipStream_t stream) {
    const float* x  = (const float*)d_in[0];
    const float* h0 = (const float*)d_in[1];
    const float* Wx = (const float*)d_in[2];
    const float* Wh = (const float*)d_in[3];
    const float* b  = (const float*)d_in[4];
    float* out = (float*)d_out;

    _Float16* WxT = (_Float16*)d_ws;
    _Float16* WhT = WxT + 1024 * 1024;
    unsigned int* bar = (unsigned int*)((char*)d_ws + 4u * 1024u * 1024u);

    prep_kernel<<<2048, 256, 0, stream>>>(Wx, Wh, WxT, WhT, bar);
    gemm_xw<<<4096, 256, 0, stream>>>(x, WxT, b, out);
    rnn_scan<<<256, 256, 0, stream>>>(h0, WhT, out, bar);
}

// Round 2
// 2999.054 us; speedup vs baseline: 4.0540x; 4.0540x over previous
//
#include <hip/hip_runtime.h>

typedef _Float16 half8 __attribute__((ext_vector_type(8)));
typedef _Float16 half4v __attribute__((ext_vector_type(4)));
typedef float floatx4 __attribute__((ext_vector_type(4)));
typedef float floatx2 __attribute__((ext_vector_type(2)));

#define MFMA16(a, b, c) __builtin_amdgcn_mfma_f32_16x16x32_f16(a, b, c, 0, 0, 0)

// ws layout: [0,2MB) WxT fp16 (1024x1024, [j][d]); [2MB,4MB) WhT fp16 ([j][k]);
// [4MB, +1KB) barrier counters (group g at +g*32 uints = 128B apart).

// ---------------- prep: transpose Wx,Wh -> fp16, zero barrier counters ----------------
__global__ __launch_bounds__(256) void prep_kernel(
    const float* __restrict__ Wx, const float* __restrict__ Wh,
    _Float16* __restrict__ WxT, _Float16* __restrict__ WhT,
    unsigned int* __restrict__ bar)
{
    __shared__ float tile[32][33];
    int bid = blockIdx.x;
    int tid = threadIdx.x;
    if (bid == 0) bar[tid] = 0u;
    const float* src = (bid < 1024) ? Wx : Wh;
    _Float16* dst = (bid < 1024) ? WxT : WhT;
    int tb = bid & 1023;
    int d0 = (tb >> 5) << 5;   // source row tile (k dim)
    int j0 = (tb & 31) << 5;   // source col tile (j dim)
    int r  = tid >> 3;         // 0..31
    int c4 = (tid & 7) << 2;   // 0,4,..,28
    float4 v = *(const float4*)(src + (long)(d0 + r) * 1024 + j0 + c4);
    tile[r][c4 + 0] = v.x; tile[r][c4 + 1] = v.y;
    tile[r][c4 + 2] = v.z; tile[r][c4 + 3] = v.w;
    __syncthreads();
    half4v o;
    o[0] = (_Float16)tile[c4 + 0][r];
    o[1] = (_Float16)tile[c4 + 1][r];
    o[2] = (_Float16)tile[c4 + 2][r];
    o[3] = (_Float16)tile[c4 + 3][r];
    *(half4v*)(dst + (long)(j0 + r) * 1024 + d0 + c4) = o;
}

// ---------------- phase 1: out[r][j] = b[j] + sum_d x[r][d]*Wx[d][j] ----------------
#define LDA 40  // halves per A row in LDS (32 + 8 pad)

__global__ __launch_bounds__(256, 2) void gemm_xw(
    const float* __restrict__ x, const _Float16* __restrict__ WxT,
    const float* __restrict__ bias, float* __restrict__ out)
{
    __shared__ _Float16 As[128 * LDA];   // 10 KB
    __shared__ _Float16 Bs[128 * 32];    // 8 KB, chunk-swizzled
    int tid = threadIdx.x;
    int lane = tid & 63;
    int w = tid >> 6;
    int q = lane >> 4;
    int l16 = lane & 15;
    int wm = w >> 1, wn = w & 1;
    int bm = blockIdx.x >> 3;
    int bn = blockIdx.x & 7;
    long M0 = (long)bm * 128;
    int N0 = bn << 7;

    floatx4 acc[4][4] = {};

    int arow = tid >> 1;
    int ahalf = tid & 1;
    const float* aptr = x + (M0 + arow) * 1024 + (ahalf << 4);
    _Float16* awr = As + arow * LDA + (ahalf << 4);

    for (int kb = 0; kb < 32; ++kb) {
        __syncthreads();
        // stage A: 128x32 fp32 -> fp16
        {
            const float4* ap = (const float4*)(aptr + (kb << 5));
            float4 v0 = ap[0], v1 = ap[1], v2 = ap[2], v3 = ap[3];
            half8 h0v, h1v;
            h0v[0] = (_Float16)v0.x; h0v[1] = (_Float16)v0.y;
            h0v[2] = (_Float16)v0.z; h0v[3] = (_Float16)v0.w;
            h0v[4] = (_Float16)v1.x; h0v[5] = (_Float16)v1.y;
            h0v[6] = (_Float16)v1.z; h0v[7] = (_Float16)v1.w;
            h1v[0] = (_Float16)v2.x; h1v[1] = (_Float16)v2.y;
            h1v[2] = (_Float16)v2.z; h1v[3] = (_Float16)v2.w;
            h1v[4] = (_Float16)v3.x; h1v[5] = (_Float16)v3.y;
            h1v[6] = (_Float16)v3.z; h1v[7] = (_Float16)v3.w;
            *(half8*)(awr) = h0v;
            *(half8*)(awr + 8) = h1v;
        }
        // stage B: Bs chunk (j, cp) holds global k-chunk c = cp ^ ((j>>1)&3)
        #pragma unroll
        for (int i = 0; i < 2; ++i) {
            int chunkid = (i << 8) + tid;       // 0..511
            int j = chunkid >> 2;               // 0..127
            int cp = chunkid & 3;
            int c = cp ^ ((j >> 1) & 3);
            uint4 vv = *(const uint4*)(WxT + (long)(N0 + j) * 1024 + (kb << 5) + (c << 3));
            *(uint4*)(Bs + (chunkid << 3)) = vv;
        }
        __syncthreads();
        half8 af[4], bf[4];
        #pragma unroll
        for (int i = 0; i < 4; ++i)
            af[i] = *(const half8*)(As + (wm * 64 + i * 16 + l16) * LDA + q * 8);
        #pragma unroll
        for (int jt = 0; jt < 4; ++jt) {
            int jr = wn * 64 + jt * 16 + l16;
            int cp = q ^ ((jr >> 1) & 3);
            bf[jt] = *(const half8*)(Bs + jr * 32 + cp * 8);
        }
        #pragma unroll
        for (int i = 0; i < 4; ++i) {
            #pragma unroll
            for (int jt = 0; jt < 4; ++jt)
                acc[i][jt] = MFMA16(af[i], bf[jt], acc[i][jt]);
        }
    }
    // epilogue: C[row=q*4+reg][col=l16] per 16x16 tile; add bias
    #pragma unroll
    for (int jt = 0; jt < 4; ++jt) {
        int col = N0 + wn * 64 + jt * 16 + l16;
        float bv = bias[col];
        #pragma unroll
        for (int i = 0; i < 4; ++i) {
            long row = M0 + wm * 64 + i * 16 + q * 4;
            #pragma unroll
            for (int r2 = 0; r2 < 4; ++r2)
                out[(row + r2) * 1024 + col] = acc[i][jt][r2] + bv;
        }
    }
}

// ---------------- coherent (device coherence point) memory helpers ----------------
// 16 pipelined coherent 16B loads: dst[2*kc+i] = p[kc*32 + i*4] (floats), kc=0..7
__device__ __forceinline__ void coh_load16(const float* p, floatx4* r) {
    asm volatile(
        "global_load_dwordx4 %0, %16, off sc0 sc1\n\t"
        "global_load_dwordx4 %1, %16, off offset:16 sc0 sc1\n\t"
        "global_load_dwordx4 %2, %16, off offset:128 sc0 sc1\n\t"
        "global_load_dwordx4 %3, %16, off offset:144 sc0 sc1\n\t"
        "global_load_dwordx4 %4, %16, off offset:256 sc0 sc1\n\t"
        "global_load_dwordx4 %5, %16, off offset:272 sc0 sc1\n\t"
        "global_load_dwordx4 %6, %16, off offset:384 sc0 sc1\n\t"
        "global_load_dwordx4 %7, %16, off offset:400 sc0 sc1\n\t"
        "global_load_dwordx4 %8, %16, off offset:512 sc0 sc1\n\t"
        "global_load_dwordx4 %9, %16, off offset:528 sc0 sc1\n\t"
        "global_load_dwordx4 %10, %16, off offset:640 sc0 sc1\n\t"
        "global_load_dwordx4 %11, %16, off offset:656 sc0 sc1\n\t"
        "global_load_dwordx4 %12, %16, off offset:768 sc0 sc1\n\t"
        "global_load_dwordx4 %13, %16, off offset:784 sc0 sc1\n\t"
        "global_load_dwordx4 %14, %16, off offset:896 sc0 sc1\n\t"
        "global_load_dwordx4 %15, %16, off offset:912 sc0 sc1\n\t"
        "s_waitcnt vmcnt(0)"
        : "=&v"(r[0]), "=&v"(r[1]), "=&v"(r[2]), "=&v"(r[3]),
          "=&v"(r[4]), "=&v"(r[5]), "=&v"(r[6]), "=&v"(r[7]),
          "=&v"(r[8]), "=&v"(r[9]), "=&v"(r[10]), "=&v"(r[11]),
          "=&v"(r[12]), "=&v"(r[13]), "=&v"(r[14]), "=&v"(r[15])
        : "v"(p)
        : "memory");
}

__device__ __forceinline__ void coh_store2(float* p, floatx2 v) {
    asm volatile("global_store_dwordx2 %0, %1, off sc0 sc1"
                 :: "v"(p), "v"(v) : "memory");
}

__device__ __forceinline__ void vm_drain() {
    asm volatile("s_waitcnt vmcnt(0)" ::: "memory");
}

// ---------------- phase 2: persistent scan, h_t = tanh(xw_t + h_{t-1} @ Wh) ----------------
// 256 blocks: group g = bid>>5 owns rows [g*16,+16); block c = bid&31 owns cols [c*32,+32).
// Wh col-slice resident in LDS for all 512 steps. h communicated ONLY via sc0/sc1
// coherence-point accesses; barrier = relaxed agent atomics (no wbl2/inv anywhere).
#define WROW 1032  // halves per Wh LDS row (1024 + 8 pad)

__global__ __launch_bounds__(256, 1) void rnn_scan(
    const float* __restrict__ h0, const _Float16* __restrict__ WhT,
    float* __restrict__ out, unsigned int* __restrict__ bar)
{
    __shared__ _Float16 whs[32 * WROW];  // ~66 KB
    __shared__ float red[4 * 512];       // 8 KB
    int tid = threadIdx.x;
    int lane = tid & 63, w = tid >> 6;
    int q = lane >> 4, l16 = lane & 15;
    int g = blockIdx.x >> 5, c = blockIdx.x & 31;
    int n0 = g << 4, j0 = c << 5;
    unsigned int* cnt = bar + g * 32;

    // load Wh slice once: whs[jl][k] = Wh[k][j0+jl] (from WhT[j0+jl][k])
    for (int i = tid; i < 32 * 128; i += 256) {
        int jl = i >> 7, ch = i & 127;
        *(uint4*)(whs + jl * WROW + (ch << 3)) =
            *(const uint4*)(WhT + (long)(j0 + jl) * 1024 + (ch << 3));
    }
    __syncthreads();

    const long ST = 512L * 1024L;  // out row stride per n
    int mrow = tid >> 4;           // 0..15  (reduction/output row)
    int jl = (tid & 15) << 1;      // even col in [0,32)
    float* xwbase = out + (long)(n0 + mrow) * ST + j0 + jl;

    for (int t = 0; t < 512; ++t) {
        // prefetch xw_t (normal cached load) — overlaps the barrier spin
        const float* xwp = xwbase + (long)t * 1024;
        floatx2 xwv = *(const floatx2*)xwp;

        if (t > 0) {
            if (tid == 0) {
                unsigned int target = (unsigned int)t * 32u;
                while (__hip_atomic_load(cnt, __ATOMIC_RELAXED,
                                         __HIP_MEMORY_SCOPE_AGENT) < target)
                    __builtin_amdgcn_s_sleep(1);
            }
            __syncthreads();
        }

        // coherent h-slab load: row n0+l16, k-range [w*256 + q*8 + kc*32)
        const float* hp;
        if (t == 0) hp = h0 + (long)(n0 + l16) * 1024 + (w << 8) + (q << 3);
        else        hp = out + (long)(n0 + l16) * ST + (long)(t - 1) * 1024 + (w << 8) + (q << 3);
        floatx4 rr[16];
        coh_load16(hp, rr);

        floatx4 acc0 = {0.f, 0.f, 0.f, 0.f};
        floatx4 acc1 = {0.f, 0.f, 0.f, 0.f};
        #pragma unroll
        for (int kc = 0; kc < 8; ++kc) {
            floatx4 v0 = rr[2 * kc], v1 = rr[2 * kc + 1];
            half8 a;
            a[0] = (_Float16)v0[0]; a[1] = (_Float16)v0[1];
            a[2] = (_Float16)v0[2]; a[3] = (_Float16)v0[3];
            a[4] = (_Float16)v1[0]; a[5] = (_Float16)v1[1];
            a[6] = (_Float16)v1[2]; a[7] = (_Float16)v1[3];
            int koff = (w << 8) + (kc << 5) + (q << 3);
            half8 b0 = *(const half8*)(whs + l16 * WROW + koff);
            half8 b1 = *(const half8*)(whs + (16 + l16) * WROW + koff);
            acc0 = MFMA16(a, b0, acc0);
            acc1 = MFMA16(a, b1, acc1);
        }
        // cross-wave K reduction via LDS
        #pragma unroll
        for (int r2 = 0; r2 < 4; ++r2) {
            int m = (q << 2) + r2;
            red[(w << 9) + (m << 5) + l16]      = acc0[r2];
            red[(w << 9) + (m << 5) + 16 + l16] = acc1[r2];
        }
        __syncthreads();
        {
            int idx = (mrow << 5) + jl;
            float s0 = red[idx] + red[512 + idx] + red[1024 + idx] + red[1536 + idx];
            float s1 = red[idx + 1] + red[512 + idx + 1] + red[1024 + idx + 1] + red[1536 + idx + 1];
            floatx2 hv;
            hv[0] = tanhf(s0 + xwv[0]);
            hv[1] = tanhf(s1 + xwv[1]);
            coh_store2((float*)xwp, hv);  // h_t overwrites xw_t at coherence point
        }
        vm_drain();        // own coherent stores performed at MALL
        __syncthreads();   // => whole block's stores performed
        if (tid == 0)
            __hip_atomic_fetch_add(cnt, 1u, __ATOMIC_RELAXED, __HIP_MEMORY_SCOPE_AGENT);
    }
}

extern "C" void kernel_launch(void* const* d_in, const int* in_sizes, int n_in,
                              void* d_out, int out_size, void* d_ws, size_t ws_size,
                              hipStream_t stream) {
    const float* x  = (const float*)d_in[0];
    const float* h0 = (const float*)d_in[1];
    const float* Wx = (const float*)d_in[2];
    const float* Wh = (const float*)d_in[3];
    const float* b  = (const float*)d_in[4];
    float* out = (float*)d_out;

    _Float16* WxT = (_Float16*)d_ws;
    _Float16* WhT = WxT + 1024 * 1024;
    unsigned int* bar = (unsigned int*)((char*)d_ws + 4u * 1024u * 1024u);

    prep_kernel<<<2048, 256, 0, stream>>>(Wx, Wh, WxT, WhT, bar);
    gemm_xw<<<4096, 256, 0, stream>>>(x, WxT, b, out);
    rnn_scan<<<256, 256, 0, stream>>>(h0, WhT, out, bar);
}